// Round 2
// baseline (295.151 us; speedup 1.0000x reference)
//
#include <hip/hip_runtime.h>
#include <math.h>

// y_t = clamp(y_{t-1}, x_t, x_t+1): play operator as associative clamp-scan.
// compose is min/max-only => exact => any grouping is bit-identical (deterministic).
// Single-pass decoupled lookback: read input once, write output once.

#define TPB 256
#define EPT 32
#define EPB (TPB * EPT)   // 8192 elements per block

struct Pair { float a, b; };

__device__ __forceinline__ Pair compose(Pair l, Pair r) {
    Pair o;
    o.a = fminf(fmaxf(l.a, r.a), r.b);
    o.b = fminf(fmaxf(l.b, r.a), r.b);
    return o;
}
__device__ __forceinline__ Pair ident() {
    Pair p; p.a = -INFINITY; p.b = INFINITY; return p;
}

__global__ __launch_bounds__(TPB)
void k_scan(const float* __restrict__ in, const float* __restrict__ kptr,
            int* counter, int* flags,
            float* agg_a, float* agg_b, float* pre_a, float* pre_b,
            float* __restrict__ out, int n) {
    __shared__ int svid;
    __shared__ Pair wagg[TPB / 64];
    __shared__ Pair sE;

    // dynamic block id in dispatch-start order (lookback forward progress)
    if (threadIdx.x == 0)
        svid = __hip_atomic_fetch_add(counter, 1, __ATOMIC_RELAXED, __HIP_MEMORY_SCOPE_AGENT);
    __syncthreads();
    const int vid  = svid;
    const int lane = threadIdx.x & 63;
    const int wid  = threadIdx.x >> 6;
    const float k  = kptr[0];
    const int base = vid * EPB + (int)threadIdx.x * EPT;

    // ---- load 32 elements, keep in registers for the apply phase ----
    float xs[EPT];
    int m = 0;
    if (base + EPT <= n) {
        m = EPT;
        #pragma unroll
        for (int v = 0; v < EPT / 4; ++v) {
            float4 f = reinterpret_cast<const float4*>(in + base)[v];
            xs[4*v+0] = f.x; xs[4*v+1] = f.y; xs[4*v+2] = f.z; xs[4*v+3] = f.w;
        }
    } else if (base < n) {
        m = n - base;
        for (int j = 0; j < m; ++j) xs[j] = in[base + j];
    }

    // ---- thread-local ordered clamp aggregate ----
    Pair p = ident();
    #pragma unroll
    for (int j = 0; j < EPT; ++j) {
        if (j < m) {
            float lo, hi;
            if (base + j == 0) { lo = xs[j]; hi = xs[j]; }     // constant p0
            else { float xv = xs[j] * k; lo = xv; hi = xv + 1.0f; }
            p.a = fminf(fmaxf(p.a, lo), hi);
            p.b = fminf(fmaxf(p.b, lo), hi);
        }
    }

    // ---- wave-level inclusive scan (shuffles, no barriers) ----
    Pair w = p;
    #pragma unroll
    for (int off = 1; off < 64; off <<= 1) {
        Pair u;
        u.a = __shfl_up(w.a, off);
        u.b = __shfl_up(w.b, off);
        if (lane >= off) w = compose(u, w);
    }
    if (lane == 63) wagg[wid] = w;
    __syncthreads();

    Pair wpre = ident();
    #pragma unroll
    for (int i = 0; i < TPB / 64; ++i) if (i < wid) wpre = compose(wpre, wagg[i]);
    Pair bagg = wagg[0];
    #pragma unroll
    for (int i = 1; i < TPB / 64; ++i) bagg = compose(bagg, wagg[i]);

    Pair uprev;
    uprev.a = __shfl_up(w.a, 1);
    uprev.b = __shfl_up(w.b, 1);
    Pair excl = (lane == 0) ? wpre : compose(wpre, uprev);  // threads 0..tid-1

    // ---- publish block aggregate ASAP (vid 0 publishes prefix directly) ----
    if (threadIdx.x == 0 && vid > 0) {
        __hip_atomic_store(&agg_a[vid], bagg.a, __ATOMIC_RELAXED, __HIP_MEMORY_SCOPE_AGENT);
        __hip_atomic_store(&agg_b[vid], bagg.b, __ATOMIC_RELAXED, __HIP_MEMORY_SCOPE_AGENT);
        __hip_atomic_store(&flags[vid], 1, __ATOMIC_RELEASE, __HIP_MEMORY_SCOPE_AGENT);
    }

    // ---- wave-parallel decoupled lookback (wave 0 only) ----
    if (wid == 0) {
        Pair E = ident();
        if (vid > 0) {
            Pair acc = ident();          // composition of blocks (j+1 .. vid-1)
            int j = vid - 1;
            for (;;) {
                const int idx = j - lane;   // lane 0 = nearest predecessor
                int f;
                for (;;) {
                    f = (idx >= 0)
                        ? __hip_atomic_load(&flags[idx], __ATOMIC_ACQUIRE, __HIP_MEMORY_SCOPE_AGENT)
                        : 1;
                    if (__all(f != 0)) break;
                    __builtin_amdgcn_s_sleep(1);
                }
                Pair v = ident();
                if (idx >= 0) {
                    if (f == 2) {  // inclusive prefix slot (write-once, no ABA)
                        v.a = __hip_atomic_load(&pre_a[idx], __ATOMIC_RELAXED, __HIP_MEMORY_SCOPE_AGENT);
                        v.b = __hip_atomic_load(&pre_b[idx], __ATOMIC_RELAXED, __HIP_MEMORY_SCOPE_AGENT);
                    } else {       // aggregate slot
                        v.a = __hip_atomic_load(&agg_a[idx], __ATOMIC_RELAXED, __HIP_MEMORY_SCOPE_AGENT);
                        v.b = __hip_atomic_load(&agg_b[idx], __ATOMIC_RELAXED, __HIP_MEMORY_SCOPE_AGENT);
                    }
                }
                unsigned long long mask2 = __ballot(idx >= 0 && f == 2);
                const int stop = mask2 ? __builtin_ctzll(mask2) : 64;
                if (lane > stop) v = ident();   // covered by the prefix at `stop`
                // ordered tree: lane 0 ends with v63 ∘ v62 ∘ ... ∘ v0
                #pragma unroll
                for (int off = 1; off < 64; off <<= 1) {
                    Pair u;
                    u.a = __shfl_down(v.a, off);
                    u.b = __shfl_down(v.b, off);
                    if (lane + off < 64) v = compose(u, v);
                }
                if (stop < 64) {
                    if (lane == 0) E = compose(v, acc);
                    break;
                }
                if (lane == 0) acc = compose(v, acc);
                j -= 64;   // window covering idx 0 always finds flag==2 (block 0)
            }
        }
        if (lane == 0) {
            sE = E;
            Pair P = compose(E, bagg);   // E = ident for vid 0 -> P = bagg
            __hip_atomic_store(&pre_a[vid], P.a, __ATOMIC_RELAXED, __HIP_MEMORY_SCOPE_AGENT);
            __hip_atomic_store(&pre_b[vid], P.b, __ATOMIC_RELAXED, __HIP_MEMORY_SCOPE_AGENT);
            __hip_atomic_store(&flags[vid], 2, __ATOMIC_RELEASE, __HIP_MEMORY_SCOPE_AGENT);
        }
    }
    __syncthreads();

    // ---- apply: sequential clamp chain from register-resident xs ----
    Pair fin = compose(sE, excl);
    // prefixes that include element 0 are constant (a==b), so the dummy seed 0
    // is irrelevant; for block0/thread0 fin is identity and element 0 overrides.
    float y = fminf(fmaxf(0.0f, fin.a), fin.b);

    if (m == EPT) {
        #pragma unroll
        for (int v = 0; v < EPT / 4; ++v) {
            float o[4];
            #pragma unroll
            for (int jj = 0; jj < 4; ++jj) {
                const int idx = 4 * v + jj;
                float lo, hi;
                if (base + idx == 0) { lo = xs[idx]; hi = xs[idx]; }
                else { float xv = xs[idx] * k; lo = xv; hi = xv + 1.0f; }
                y = fminf(fmaxf(y, lo), hi);
                o[jj] = y;
            }
            reinterpret_cast<float4*>(out + base)[v] = make_float4(o[0], o[1], o[2], o[3]);
        }
    } else {
        for (int j = 0; j < m; ++j) {
            float lo, hi;
            if (base + j == 0) { lo = xs[j]; hi = xs[j]; }
            else { float xv = xs[j] * k; lo = xv; hi = xv + 1.0f; }
            y = fminf(fmaxf(y, lo), hi);
            out[base + j] = y;
        }
    }
}

extern "C" void kernel_launch(void* const* d_in, const int* in_sizes, int n_in,
                              void* d_out, int out_size, void* d_ws, size_t ws_size,
                              hipStream_t stream) {
    const float* in   = (const float*)d_in[0];   // [T+1], in[0] = p0
    const float* kptr = (const float*)d_in[1];   // scalar weight
    float* out = (float*)d_out;                  // [T+1]
    const int n  = in_sizes[0];
    const int nb = (n + EPB - 1) / EPB;          // 2049 for T=2^24

    char* ws     = (char*)d_ws;
    int* counter = (int*)ws;                     // offset 0
    int* flags   = (int*)(ws + 64);              // nb ints
    size_t off   = 64 + (((size_t)nb * 4 + 63) & ~(size_t)63);
    float* agg_a = (float*)(ws + off);
    float* agg_b = agg_a + nb;
    float* pre_a = agg_b + nb;
    float* pre_b = pre_a + nb;

    // zero counter + flags each call (harness poisons ws; graph-capture safe)
    (void)hipMemsetAsync(d_ws, 0, 64 + (size_t)nb * 4, stream);
    k_scan<<<nb, TPB, 0, stream>>>(in, kptr, counter, flags,
                                   agg_a, agg_b, pre_a, pre_b, out, n);
}

// Round 3
// 51.281 us; speedup vs baseline: 5.7555x; 5.7555x over previous
//
#include <hip/hip_runtime.h>
#include <math.h>

// y_t = clamp(y_{t-1}, x_t, x_t+1): play operator as associative clamp-scan.
// compose(l, r) = "apply l first, then r" = clamp l's outputs by r's window.
// min/max-only => exact => any regrouping is bit-identical (deterministic).
//
// Two passes, no atomics:
//   pass 1: per-block ordered aggregate -> agg[nb] (32 KB, L2-resident)
//   pass 2: each block redundantly computes its exclusive prefix over agg[]
//           (cheap L2 reads), then applies the clamp chain and writes out.

#define TPB 256
#define EPT 16
#define EPB (TPB * EPT)   // 4096 elements per block

struct Pair { float a, b; };

__device__ __forceinline__ Pair compose(Pair l, Pair r) {
    Pair o;
    o.a = fminf(fmaxf(l.a, r.a), r.b);
    o.b = fminf(fmaxf(l.b, r.a), r.b);
    return o;
}
__device__ __forceinline__ Pair ident() {
    Pair p; p.a = -INFINITY; p.b = INFINITY; return p;
}

// element e -> clamp window (lo,hi). e==0 is the constant function (p0,p0).
__device__ __forceinline__ void elem_window(int e, float x, float k,
                                            float& lo, float& hi) {
    if (e == 0) { lo = x; hi = x; }
    else { float xv = x * k; lo = xv; hi = xv + 1.0f; }
}

// ---------------- pass 1: per-block ordered aggregate ----------------------
__global__ __launch_bounds__(TPB)
void k_reduce(const float* __restrict__ in, const float* __restrict__ kptr,
              float2* __restrict__ agg, int n) {
    const float k = kptr[0];
    const int tid  = threadIdx.x;
    const int lane = tid & 63;
    const int wid  = tid >> 6;
    const int base = blockIdx.x * EPB + tid * EPT;

    float xs[EPT];
    const bool full = (base + EPT <= n);
    if (full) {
        #pragma unroll
        for (int v = 0; v < EPT / 4; ++v) {
            float4 f = reinterpret_cast<const float4*>(in + base)[v];
            xs[4*v+0] = f.x; xs[4*v+1] = f.y; xs[4*v+2] = f.z; xs[4*v+3] = f.w;
        }
    } else {
        #pragma unroll
        for (int j = 0; j < EPT; ++j)          // static j: stays in registers
            xs[j] = (base + j < n) ? in[base + j] : 0.0f;
    }

    Pair p = ident();
    #pragma unroll
    for (int j = 0; j < EPT; ++j) {
        if (base + j < n) {
            float lo, hi;
            elem_window(base + j, xs[j], k, lo, hi);
            p.a = fminf(fmaxf(p.a, lo), hi);
            p.b = fminf(fmaxf(p.b, lo), hi);
        }
    }

    // ordered wave inclusive scan; lane 63 holds the wave aggregate
    Pair w = p;
    #pragma unroll
    for (int off = 1; off < 64; off <<= 1) {
        Pair u;
        u.a = __shfl_up(w.a, off);
        u.b = __shfl_up(w.b, off);
        if (lane >= off) w = compose(u, w);
    }
    __shared__ Pair wagg[TPB / 64];
    if (lane == 63) wagg[wid] = w;
    __syncthreads();
    if (tid == 0) {
        Pair b = wagg[0];
        #pragma unroll
        for (int i = 1; i < TPB / 64; ++i) b = compose(b, wagg[i]);
        agg[blockIdx.x] = make_float2(b.a, b.b);
    }
}

// ---------------- pass 2: redundant prefix + apply -------------------------
__global__ __launch_bounds__(TPB)
void k_apply(const float* __restrict__ in, const float* __restrict__ kptr,
             const float2* __restrict__ agg, float* __restrict__ out, int n) {
    const float k = kptr[0];
    const int tid  = threadIdx.x;
    const int lane = tid & 63;
    const int wid  = tid >> 6;
    const int vid  = blockIdx.x;
    const int base = vid * EPB + tid * EPT;

    // issue input loads FIRST so HBM/IF latency hides under the prefix work
    float xs[EPT];
    const bool full = (base + EPT <= n);
    if (full) {
        #pragma unroll
        for (int v = 0; v < EPT / 4; ++v) {
            float4 f = reinterpret_cast<const float4*>(in + base)[v];
            xs[4*v+0] = f.x; xs[4*v+1] = f.y; xs[4*v+2] = f.z; xs[4*v+3] = f.w;
        }
    } else {
        #pragma unroll
        for (int j = 0; j < EPT; ++j)          // static j: stays in registers
            xs[j] = (base + j < n) ? in[base + j] : 0.0f;
    }

    // ---- exclusive block prefix E = agg[0] ∘ agg[1] ∘ ... ∘ agg[vid-1] ----
    Pair p = ident();
    if (vid > 0) {
        const int seg = (vid + TPB - 1) >> 8;      // ceil(vid / 256)
        const int lo  = tid * seg;
        const int hi  = min(lo + seg, vid);
        for (int i = lo; i < hi; ++i) {            // ordered within thread
            float2 g = agg[i];
            Pair r; r.a = g.x; r.b = g.y;
            p = compose(p, r);
        }
    }
    Pair w = p;
    #pragma unroll
    for (int off = 1; off < 64; off <<= 1) {
        Pair u;
        u.a = __shfl_up(w.a, off);
        u.b = __shfl_up(w.b, off);
        if (lane >= off) w = compose(u, w);
    }
    __shared__ Pair wpre[TPB / 64];
    if (lane == 63) wpre[wid] = w;
    __syncthreads();
    Pair E = wpre[0];
    #pragma unroll
    for (int i = 1; i < TPB / 64; ++i) E = compose(E, wpre[i]);  // same in all threads

    // ---- within-block exclusive prefix over thread aggregates ----
    Pair tp = ident();
    #pragma unroll
    for (int j = 0; j < EPT; ++j) {
        if (base + j < n) {
            float lo, hi;
            elem_window(base + j, xs[j], k, lo, hi);
            tp.a = fminf(fmaxf(tp.a, lo), hi);
            tp.b = fminf(fmaxf(tp.b, lo), hi);
        }
    }
    Pair tw = tp;
    #pragma unroll
    for (int off = 1; off < 64; off <<= 1) {
        Pair u;
        u.a = __shfl_up(tw.a, off);
        u.b = __shfl_up(tw.b, off);
        if (lane >= off) tw = compose(u, tw);
    }
    __shared__ Pair wagg[TPB / 64];
    if (lane == 63) wagg[wid] = tw;
    __syncthreads();
    Pair wpref = ident();
    #pragma unroll
    for (int i = 0; i < TPB / 64; ++i) if (i < wid) wpref = compose(wpref, wagg[i]);
    Pair uprev;
    uprev.a = __shfl_up(tw.a, 1);
    uprev.b = __shfl_up(tw.b, 1);
    Pair excl = (lane == 0) ? wpref : compose(wpref, uprev);

    Pair fin = compose(E, excl);
    // Any prefix containing element 0 is a constant function (a==b), so the
    // dummy seed 0 is irrelevant; for block0/thread0 fin is the identity and
    // element 0 (constant p0) overrides y on the first step.
    float y = fminf(fmaxf(0.0f, fin.a), fin.b);

    if (full) {
        #pragma unroll
        for (int v = 0; v < EPT / 4; ++v) {
            float o[4];
            #pragma unroll
            for (int jj = 0; jj < 4; ++jj) {
                const int idx = 4 * v + jj;
                float lo, hi;
                elem_window(base + idx, xs[idx], k, lo, hi);
                y = fminf(fmaxf(y, lo), hi);
                o[jj] = y;
            }
            reinterpret_cast<float4*>(out + base)[v] =
                make_float4(o[0], o[1], o[2], o[3]);
        }
    } else {
        #pragma unroll
        for (int j = 0; j < EPT; ++j) {        // static j: no scratch
            if (base + j < n) {
                float lo, hi;
                elem_window(base + j, xs[j], k, lo, hi);
                y = fminf(fmaxf(y, lo), hi);
                out[base + j] = y;
            }
        }
    }
}

extern "C" void kernel_launch(void* const* d_in, const int* in_sizes, int n_in,
                              void* d_out, int out_size, void* d_ws, size_t ws_size,
                              hipStream_t stream) {
    const float* in   = (const float*)d_in[0];   // [T+1], in[0] = p0
    const float* kptr = (const float*)d_in[1];   // scalar weight
    float* out = (float*)d_out;                  // [T+1]
    const int n  = in_sizes[0];
    const int nb = (n + EPB - 1) / EPB;          // 4097 for T = 2^24

    float2* agg = (float2*)d_ws;                 // nb aggregates (32 KB)

    k_reduce<<<nb, TPB, 0, stream>>>(in, kptr, agg, n);
    k_apply <<<nb, TPB, 0, stream>>>(in, kptr, agg, out, n);
}